// Round 10
// baseline (230.442 us; speedup 1.0000x reference)
//
#include <hip/hip_runtime.h>

#define N_NODES 100000
#define N_EDGES 1600000
#define NB 391            // ceil(N_NODES/256) row-buckets of 256 rows
#define NBLK 256          // blocks for binning pass
#define CHUNK 6250        // ceil(N_EDGES/NBLK)
#define CAP 5120          // per-bucket binbuf capacity (mean 4096, sigma 64)

typedef unsigned int uint;
typedef __attribute__((ext_vector_type(8))) short short8v;  // 8 bf16 (4 VGPRs)
typedef __attribute__((ext_vector_type(4))) float f32x4;

// ---------------- bf16 helpers ----------------

__device__ __forceinline__ uint bfrn(float x) {  // fp32 -> bf16 bits (RN)
  uint u = __float_as_uint(x);
  u += 0x7fffu + ((u >> 16) & 1u);
  return u >> 16;
}
__device__ __forceinline__ uint bfpack(float a, float b) {
  return bfrn(a) | (bfrn(b) << 16);
}
__device__ __forceinline__ float bflo(uint u) { return __uint_as_float(u << 16); }
__device__ __forceinline__ float bfhi(uint u) { return __uint_as_float(u & 0xffff0000u); }

// ---------------- kernel A: binning (blocks 0-255) + weight packs (256-351) -------
// gcur zero-init by hipMemsetAsync; reservation slot = i*CAP + atomicAdd(gcur[i],c).
// Packed B-fragment index for element (k,f), NCT=FOUT/16:
//   ks=k>>5, j=k&7, lq=(k>>3)&3, lane=(lq<<4)|(f&15), ct=f>>4
//   idx = ((ks*NCT + ct)*64 + lane)*8 + j

__global__ __launch_bounds__(256) void combo_k(const int* __restrict__ ei,
                                               int* __restrict__ gcur,
                                               unsigned* __restrict__ binbuf,
                                               const float* __restrict__ W0,
                                               const float* __restrict__ W1,
                                               const float* __restrict__ W2,
                                               unsigned short* __restrict__ W01p,
                                               unsigned short* __restrict__ W2p) {
  int b = blockIdx.x;
  if (b < NBLK) {
    __shared__ int lh[NB];
    for (int i = threadIdx.x; i < NB; i += 256) lh[i] = 0;
    __syncthreads();
    int ebeg = b * CHUNK, e1 = min(ebeg + CHUNK, N_EDGES);
    for (int e = ebeg + threadIdx.x; e < e1; e += 256) {
      atomicAdd(&lh[ei[e] >> 8], 1);
    }
    __syncthreads();
    for (int i = threadIdx.x; i < NB; i += 256) {
      int c = lh[i];
      lh[i] = c ? (i * CAP + atomicAdd(&gcur[i], c)) : 0;
    }
    __syncthreads();
    for (int e = ebeg + threadIdx.x; e < e1; e += 256) {
      int r = ei[e];
      int c = ei[N_EDGES + e];
      int p = atomicAdd(&lh[r >> 8], 1);
      binbuf[p] = ((unsigned)(r & 255) << 24) | (unsigned)c;  // c < 2^17 fits
    }
  } else if (b < NBLK + 64) {
    int g = (b - NBLK) * 256 + threadIdx.x;  // 16384: W01 = W0@W1
    int k = g >> 7, f = g & 127;
    float s = 0.f;
    for (int kk = 0; kk < 128; kk++) s = fmaf(W0[k * 128 + kk], W1[kk * 128 + f], s);
    int ks = k >> 5, j = k & 7, lq = (k >> 3) & 3;
    int lane = (lq << 4) | (f & 15), ct = f >> 4;
    W01p[((ks * 8 + ct) * 64 + lane) * 8 + j] = (unsigned short)bfrn(s);
  } else {
    int g = (b - NBLK - 64) * 256 + threadIdx.x;  // 8192: W2
    int k = g >> 6, f = g & 63;
    int ks = k >> 5, j = k & 7, lq = (k >> 3) & 3;
    int lane = (lq << 4) | (f & 15), ct = f >> 4;
    W2p[((ks * 4 + ct) * 64 + lane) * 8 + j] = (unsigned short)bfrn(W2[k * 64 + f]);
  }
}

// ---------------- kernel B: per-bucket CSR build + mgemm128 (4 tiles) -------------
// Block k: count/scan bucket k -> off/dinv/cc, then x0b rows 256k..256k+255 =
// bf16(dinv ⊙ (feat @ W01)) via MFMA.

__global__ __launch_bounds__(256) void buckgemm_k(const unsigned* __restrict__ binbuf,
                                                  const int* __restrict__ gcur,
                                                  const float* __restrict__ feat,
                                                  const unsigned short* __restrict__ W01p,
                                                  int* __restrict__ off,
                                                  float* __restrict__ dinv,
                                                  uint* __restrict__ cc,
                                                  unsigned short* __restrict__ x0b) {
  __shared__ int cnt[256];
  __shared__ int sc[256];
  __shared__ float sdinv[256];
  __shared__ int sbase_s;
  __shared__ uint4 Al4[64 * 16];    // 16 KB A tile (swizzled bf16)
  __shared__ uint4 Wl4[128 * 16];   // 32 KB packed W01 fragments
  char* Al = (char*)Al4;
  int k = blockIdx.x, row0n = k << 8, tid = threadIdx.x;
  if (tid < 64) {  // sbase = sum_{j<k} count_j
    int s = 0;
    for (int j = tid; j < k; j += 64) s += gcur[j];
#pragma unroll
    for (int d = 32; d; d >>= 1) s += __shfl_xor(s, d);
    if (tid == 0) sbase_s = s;
  }
  cnt[tid] = 0;
  __syncthreads();
  int n = gcur[k];
  int sb = k * CAP;
  for (int t = tid; t < n; t += 256) atomicAdd(&cnt[binbuf[sb + t] >> 24], 1);
  __syncthreads();
  int v = cnt[tid];
  sc[tid] = v;
  __syncthreads();
  for (int d = 1; d < 256; d <<= 1) {
    int t = (tid >= d) ? sc[tid - d] : 0;
    __syncthreads();
    sc[tid] += t;
    __syncthreads();
  }
  int row = row0n + tid;
  int mystart = sbase_s + sc[tid] - v;
  float dv = rsqrtf((float)v + 1.0f);  // +1 = self-loop
  sdinv[tid] = dv;
  if (row < N_NODES) {
    off[row] = mystart;
    dinv[row] = dv;
  }
  if (k == NB - 1 && tid == 0) off[N_NODES] = N_EDGES;
  __syncthreads();
  cnt[tid] = mystart;  // reuse as placement cursor
  __syncthreads();
  for (int t = tid; t < n; t += 256) {
    unsigned u = binbuf[sb + t];
    int slot = atomicAdd(&cnt[u >> 24], 1);
    cc[slot] = u & 0xFFFFFFu;
  }
  // ---- GEMM phase: 4 tiles of 64 rows ----
  for (int i = tid; i < 128 * 16; i += 256) Wl4[i] = ((const uint4*)W01p)[i];
  int lane = tid & 63, w = tid >> 6;
  const float4* Af = (const float4*)feat;
  for (int t = 0; t < 4; t++) {
    int trow0 = row0n + t * 64;
    for (int i = tid; i < 64 * 32; i += 256) {
      int r = i >> 5, c4 = i & 31;
      int gr = trow0 + r;
      float4 vv = make_float4(0.f, 0.f, 0.f, 0.f);
      if (gr < N_NODES) vv = Af[(uint)gr * 32u + c4];
      uint2 p;
      p.x = bfpack(vv.x, vv.y);
      p.y = bfpack(vv.z, vv.w);
      int byte = (r * 256 + c4 * 8) ^ ((r & 7) << 4);
      *(uint2*)(Al + byte) = p;
    }
    __syncthreads();
    f32x4 acc[8];
#pragma unroll
    for (int ct = 0; ct < 8; ct++) acc[ct] = (f32x4){0.f, 0.f, 0.f, 0.f};
    int arow = w * 16 + (lane & 15);
#pragma unroll
    for (int ks = 0; ks < 4; ks++) {
      int abyte = (arow * 256 + ks * 64 + (lane >> 4) * 16) ^ ((arow & 7) << 4);
      short8v a = *(const short8v*)(Al + abyte);
#pragma unroll
      for (int ct = 0; ct < 8; ct++) {
        short8v bb = *(const short8v*)((const char*)Wl4 + ((ks * 8 + ct) * 64 + lane) * 16);
        acc[ct] = __builtin_amdgcn_mfma_f32_16x16x32_bf16(a, bb, acc[ct], 0, 0, 0);
      }
    }
#pragma unroll
    for (int j = 0; j < 4; j++) {
      int lr = w * 16 + ((lane >> 4) << 2) + j;
      int grow = trow0 + lr;
      if (grow < N_NODES) {
        float scale = sdinv[t * 64 + lr];
#pragma unroll
        for (int ct = 0; ct < 8; ct++) {
          x0b[(uint)grow * 128u + ct * 16 + (lane & 15)] =
              (unsigned short)bfrn(acc[ct][j] * scale);
        }
      }
    }
    __syncthreads();  // Al reuse guard
  }
}

// ---------------- kernel C: prop128 (gather) fused with mgemm64 -------------------
// Block = 64 nodes. 4 waves x 16 sequential nodes; relu'd bf16 results into
// swizzled LDS A-tile; then t2b = bf16(dinv ⊙ (A @ W2)) via MFMA.

__global__ __launch_bounds__(256) void propgemm64_k(const uint2* __restrict__ X,  // x0b
                                                    const int* __restrict__ off,
                                                    const uint* __restrict__ cc,
                                                    const float* __restrict__ dinv,
                                                    const unsigned short* __restrict__ W2p,
                                                    unsigned short* __restrict__ t2b) {
  __shared__ uint4 Al4[64 * 16];  // 16 KB A tile (swizzled bf16)
  __shared__ uint4 Wl4[64 * 16];  // 16 KB packed W2 fragments
  char* Al = (char*)Al4;
  int row0 = blockIdx.x * 64;
  int tid = threadIdx.x;
  for (int i = tid; i < 64 * 16; i += 256) Wl4[i] = ((const uint4*)W2p)[i];
  int lane = tid & 63, w = tid >> 6;
  uint sub = (uint)lane >> 5, o32 = (uint)lane & 31u;
  for (int i = 0; i < 16; i++) {
    int node = row0 + w * 16 + i;
    float4 acc = make_float4(0.f, 0.f, 0.f, 0.f);
    if (node < N_NODES) {
      float di = dinv[node];
      uint2 s = X[(uint)node * 32u + o32];
      int e = off[node], e1 = off[node + 1];
      for (; e + 7 < e1; e += 8) {  // 4 pairs = 8 edges
        uint c[4];
        uint2 vv[4];
#pragma unroll
        for (int j = 0; j < 4; j++) c[j] = cc[e + 2 * j + sub];
#pragma unroll
        for (int j = 0; j < 4; j++) vv[j] = X[c[j] * 32u + o32];
#pragma unroll
        for (int j = 0; j < 4; j++) {
          acc.x += bflo(vv[j].x);
          acc.y += bfhi(vv[j].x);
          acc.z += bflo(vv[j].y);
          acc.w += bfhi(vv[j].y);
        }
      }
      for (; e + 1 < e1; e += 2) {
        uint2 vv = X[cc[e + sub] * 32u + o32];
        acc.x += bflo(vv.x);
        acc.y += bfhi(vv.x);
        acc.z += bflo(vv.y);
        acc.w += bfhi(vv.y);
      }
      if (e < e1 && sub == 0) {  // odd tail edge: half-wave only
        uint2 vv = X[cc[e] * 32u + o32];
        acc.x += bflo(vv.x);
        acc.y += bfhi(vv.x);
        acc.z += bflo(vv.y);
        acc.w += bfhi(vv.y);
      }
      acc.x += __shfl_xor(acc.x, 32);
      acc.y += __shfl_xor(acc.y, 32);
      acc.z += __shfl_xor(acc.z, 32);
      acc.w += __shfl_xor(acc.w, 32);
      acc.x = fmaxf((acc.x + bflo(s.x)) * di, 0.f);  // relu(dinv * (sum + self))
      acc.y = fmaxf((acc.y + bfhi(s.x)) * di, 0.f);
      acc.z = fmaxf((acc.z + bflo(s.y)) * di, 0.f);
      acc.w = fmaxf((acc.w + bfhi(s.y)) * di, 0.f);
    }
    if (sub == 0) {
      int r = w * 16 + i;
      uint2 p;
      p.x = bfpack(acc.x, acc.y);
      p.y = bfpack(acc.z, acc.w);
      int byte = (r * 256 + (int)o32 * 8) ^ ((r & 7) << 4);
      *(uint2*)(Al + byte) = p;
    }
  }
  __syncthreads();
  f32x4 gacc[4];
#pragma unroll
  for (int ct = 0; ct < 4; ct++) gacc[ct] = (f32x4){0.f, 0.f, 0.f, 0.f};
  int arow = w * 16 + (lane & 15);
#pragma unroll
  for (int ks = 0; ks < 4; ks++) {
    int abyte = (arow * 256 + ks * 64 + (lane >> 4) * 16) ^ ((arow & 7) << 4);
    short8v a = *(const short8v*)(Al + abyte);
#pragma unroll
    for (int ct = 0; ct < 4; ct++) {
      short8v bb = *(const short8v*)((const char*)Wl4 + ((ks * 4 + ct) * 64 + lane) * 16);
      gacc[ct] = __builtin_amdgcn_mfma_f32_16x16x32_bf16(a, bb, gacc[ct], 0, 0, 0);
    }
  }
#pragma unroll
  for (int j = 0; j < 4; j++) {
    int grow = row0 + w * 16 + ((lane >> 4) << 2) + j;
    if (grow < N_NODES) {
      float scale = dinv[grow];
#pragma unroll
      for (int ct = 0; ct < 4; ct++) {
        t2b[(uint)grow * 64u + ct * 16 + (lane & 15)] =
            (unsigned short)bfrn(gacc[ct][j] * scale);
      }
    }
  }
}

// ---------------- prop, 64 bf16 feats, coefficient-free, fp32 out -----------------

__global__ __launch_bounds__(256) void prop64s_k(const uint* __restrict__ X,  // bf16x2
                                                 float2* __restrict__ Y,
                                                 const int* __restrict__ off,
                                                 const uint* __restrict__ cc,
                                                 const float* __restrict__ dinv) {
  int node = blockIdx.x * 4 + (threadIdx.x >> 6);
  if (node >= N_NODES) return;
  uint lane = threadIdx.x & 63u;
  uint sub = lane >> 5, o32 = lane & 31u;
  float di = dinv[node];
  uint s = X[(uint)node * 32u + o32];
  float2 acc = make_float2(0.f, 0.f);
  int e = off[node], e1 = off[node + 1];
  for (; e + 7 < e1; e += 8) {
    uint c[4];
    uint v[4];
#pragma unroll
    for (int j = 0; j < 4; j++) c[j] = cc[e + 2 * j + sub];
#pragma unroll
    for (int j = 0; j < 4; j++) v[j] = X[c[j] * 32u + o32];
#pragma unroll
    for (int j = 0; j < 4; j++) {
      acc.x += bflo(v[j]);
      acc.y += bfhi(v[j]);
    }
  }
  for (; e + 1 < e1; e += 2) {
    uint v = X[cc[e + sub] * 32u + o32];
    acc.x += bflo(v);
    acc.y += bfhi(v);
  }
  if (e < e1 && sub == 0) {
    uint v = X[cc[e] * 32u + o32];
    acc.x += bflo(v);
    acc.y += bfhi(v);
  }
  acc.x += __shfl_xor(acc.x, 32);
  acc.y += __shfl_xor(acc.y, 32);
  acc.x = (acc.x + bflo(s)) * di;
  acc.y = (acc.y + bfhi(s)) * di;
  if (sub == 0) Y[(uint)node * 32u + o32] = acc;
}

// ---------------- launch ----------------
// Pipeline (uses (PX)W == P(XW) and D^-1/2 factoring):
//   memset gcur; combo: binbuf bucket-sort + W01p/W2p packs
//   buckgemm: off/dinv/cc + x0b = bf16(dinv ⊙ (feat@W01))        [MFMA]
//   propgemm64: t2b = bf16(dinv ⊙ (relu(dinv ⊙ gather(x0b)) @ W2)) [fused, MFMA]
//   prop64s: out = dinv ⊙ gather(t2b)                              (fp32)

extern "C" void kernel_launch(void* const* d_in, const int* in_sizes, int n_in,
                              void* d_out, int out_size, void* d_ws, size_t ws_size,
                              hipStream_t stream) {
  const float* feat = (const float*)d_in[0];
  const int* ei = (const int*)d_in[1];  // int32 per harness contract
  const float* W0 = (const float*)d_in[2];
  const float* W1 = (const float*)d_in[3];
  const float* W2 = (const float*)d_in[4];
  float2* out = (float2*)d_out;

  char* ws = (char*)d_ws;
  unsigned short* x0b = (unsigned short*)ws; ws += (size_t)N_NODES * 128 * 2;  // 25.6 MB
  unsigned short* t2b = (unsigned short*)ws; ws += (size_t)N_NODES * 64 * 2;   // 12.8 MB
  unsigned* binbuf = (unsigned*)ws;          ws += (size_t)NB * CAP * 4;       // 8.0 MB
  uint* cc = (uint*)ws;                      ws += (size_t)N_EDGES * 4;        // 6.4 MB
  float* dinv = (float*)ws;                  ws += (size_t)N_NODES * 4;
  int* off = (int*)ws;                       ws += (size_t)(N_NODES + 2) * 4;
  int* gcur = (int*)ws;                      ws += (size_t)NB * 4;
  unsigned short* W01p = (unsigned short*)ws; ws += 128 * 128 * 2;
  unsigned short* W2p = (unsigned short*)ws;  ws += 128 * 64 * 2;

  hipMemsetAsync(gcur, 0, (size_t)NB * 4, stream);
  combo_k<<<NBLK + 96, 256, 0, stream>>>(ei, gcur, binbuf, W0, W1, W2, W01p, W2p);
  buckgemm_k<<<NB, 256, 0, stream>>>(binbuf, gcur, feat, W01p, off, dinv, cc, x0b);
  propgemm64_k<<<(N_NODES + 63) / 64, 256, 0, stream>>>((const uint2*)x0b, off, cc, dinv,
                                                        W2p, t2b);
  prop64s_k<<<(N_NODES + 3) / 4, 256, 0, stream>>>((const uint*)t2b, out, off, cc, dinv);
}

// Round 11
// 195.734 us; speedup vs baseline: 1.1773x; 1.1773x over previous
//
#include <hip/hip_runtime.h>

#define N_NODES 100000
#define N_EDGES 1600000
#define NB 391            // ceil(N_NODES/256) row-buckets of 256 rows
#define NBLK 256          // blocks for binning pass
#define CHUNK 6250        // ceil(N_EDGES/NBLK)
#define CAP 5120          // per-bucket binbuf capacity (mean 4096, sigma 64)

typedef unsigned int uint;
typedef __attribute__((ext_vector_type(8))) short short8v;  // 8 bf16 (4 VGPRs)
typedef __attribute__((ext_vector_type(4))) float f32x4;

// ---------------- bf16 helpers ----------------

__device__ __forceinline__ uint bfrn(float x) {  // fp32 -> bf16 bits (RN)
  uint u = __float_as_uint(x);
  u += 0x7fffu + ((u >> 16) & 1u);
  return u >> 16;
}
__device__ __forceinline__ uint bfpack(float a, float b) {
  return bfrn(a) | (bfrn(b) << 16);
}
__device__ __forceinline__ float bflo(uint u) { return __uint_as_float(u << 16); }
__device__ __forceinline__ float bfhi(uint u) { return __uint_as_float(u & 0xffff0000u); }

// ---------------- kernel A: binning (blocks 0-255) + weight packs (256-351) -------
// gcur zero-init by hipMemsetAsync; reservation slot = i*CAP + atomicAdd(gcur[i],c).
// Packed B-fragment index for element (k,f), NCT=FOUT/16:
//   ks=k>>5, j=k&7, lq=(k>>3)&3, lane=(lq<<4)|(f&15), ct=f>>4
//   idx = ((ks*NCT + ct)*64 + lane)*8 + j

__global__ __launch_bounds__(256) void combo_k(const int* __restrict__ ei,
                                               int* __restrict__ gcur,
                                               unsigned* __restrict__ binbuf,
                                               const float* __restrict__ W0,
                                               const float* __restrict__ W1,
                                               const float* __restrict__ W2,
                                               unsigned short* __restrict__ W01p,
                                               unsigned short* __restrict__ W2p) {
  int b = blockIdx.x;
  if (b < NBLK) {
    __shared__ int lh[NB];
    for (int i = threadIdx.x; i < NB; i += 256) lh[i] = 0;
    __syncthreads();
    int ebeg = b * CHUNK, e1 = min(ebeg + CHUNK, N_EDGES);
    for (int e = ebeg + threadIdx.x; e < e1; e += 256) {
      atomicAdd(&lh[ei[e] >> 8], 1);
    }
    __syncthreads();
    for (int i = threadIdx.x; i < NB; i += 256) {
      int c = lh[i];
      lh[i] = c ? (i * CAP + atomicAdd(&gcur[i], c)) : 0;
    }
    __syncthreads();
    for (int e = ebeg + threadIdx.x; e < e1; e += 256) {
      int r = ei[e];
      int c = ei[N_EDGES + e];
      int p = atomicAdd(&lh[r >> 8], 1);
      binbuf[p] = ((unsigned)(r & 255) << 24) | (unsigned)c;  // c < 2^17 fits
    }
  } else if (b < NBLK + 64) {
    int g = (b - NBLK) * 256 + threadIdx.x;  // 16384: W01 = W0@W1
    int k = g >> 7, f = g & 127;
    float s = 0.f;
    for (int kk = 0; kk < 128; kk++) s = fmaf(W0[k * 128 + kk], W1[kk * 128 + f], s);
    int ks = k >> 5, j = k & 7, lq = (k >> 3) & 3;
    int lane = (lq << 4) | (f & 15), ct = f >> 4;
    W01p[((ks * 8 + ct) * 64 + lane) * 8 + j] = (unsigned short)bfrn(s);
  } else {
    int g = (b - NBLK - 64) * 256 + threadIdx.x;  // 8192: W2
    int k = g >> 6, f = g & 63;
    int ks = k >> 5, j = k & 7, lq = (k >> 3) & 3;
    int lane = (lq << 4) | (f & 15), ct = f >> 4;
    W2p[((ks * 4 + ct) * 64 + lane) * 8 + j] = (unsigned short)bfrn(W2[k * 64 + f]);
  }
}

// ---------------- kernel B: per-bucket CSR build + mgemm128 (4 tiles) -------------
// Block k: count/scan bucket k -> off/dinv/cc, then x0b rows 256k..256k+255 =
// bf16(dinv ⊙ (feat @ W01)) via MFMA.

__global__ __launch_bounds__(256) void buckgemm_k(const unsigned* __restrict__ binbuf,
                                                  const int* __restrict__ gcur,
                                                  const float* __restrict__ feat,
                                                  const unsigned short* __restrict__ W01p,
                                                  int* __restrict__ off,
                                                  float* __restrict__ dinv,
                                                  uint* __restrict__ cc,
                                                  unsigned short* __restrict__ x0b) {
  __shared__ int cnt[256];
  __shared__ int sc[256];
  __shared__ float sdinv[256];
  __shared__ int sbase_s;
  __shared__ uint4 Al4[64 * 16];    // 16 KB A tile (swizzled bf16)
  __shared__ uint4 Wl4[128 * 16];   // 32 KB packed W01 fragments
  char* Al = (char*)Al4;
  int k = blockIdx.x, row0n = k << 8, tid = threadIdx.x;
  if (tid < 64) {  // sbase = sum_{j<k} count_j
    int s = 0;
    for (int j = tid; j < k; j += 64) s += gcur[j];
#pragma unroll
    for (int d = 32; d; d >>= 1) s += __shfl_xor(s, d);
    if (tid == 0) sbase_s = s;
  }
  cnt[tid] = 0;
  __syncthreads();
  int n = gcur[k];
  int sb = k * CAP;
  for (int t = tid; t < n; t += 256) atomicAdd(&cnt[binbuf[sb + t] >> 24], 1);
  __syncthreads();
  int v = cnt[tid];
  sc[tid] = v;
  __syncthreads();
  for (int d = 1; d < 256; d <<= 1) {
    int t = (tid >= d) ? sc[tid - d] : 0;
    __syncthreads();
    sc[tid] += t;
    __syncthreads();
  }
  int row = row0n + tid;
  int mystart = sbase_s + sc[tid] - v;
  float dv = rsqrtf((float)v + 1.0f);  // +1 = self-loop
  sdinv[tid] = dv;
  if (row < N_NODES) {
    off[row] = mystart;
    dinv[row] = dv;
  }
  if (k == NB - 1 && tid == 0) off[N_NODES] = N_EDGES;
  __syncthreads();
  cnt[tid] = mystart;  // reuse as placement cursor
  __syncthreads();
  for (int t = tid; t < n; t += 256) {
    unsigned u = binbuf[sb + t];
    int slot = atomicAdd(&cnt[u >> 24], 1);
    cc[slot] = u & 0xFFFFFFu;
  }
  // ---- GEMM phase: 4 tiles of 64 rows ----
  for (int i = tid; i < 128 * 16; i += 256) Wl4[i] = ((const uint4*)W01p)[i];
  int lane = tid & 63, w = tid >> 6;
  const float4* Af = (const float4*)feat;
  for (int t = 0; t < 4; t++) {
    int trow0 = row0n + t * 64;
    for (int i = tid; i < 64 * 32; i += 256) {
      int r = i >> 5, c4 = i & 31;
      int gr = trow0 + r;
      float4 vv = make_float4(0.f, 0.f, 0.f, 0.f);
      if (gr < N_NODES) vv = Af[(uint)gr * 32u + c4];
      uint2 p;
      p.x = bfpack(vv.x, vv.y);
      p.y = bfpack(vv.z, vv.w);
      int byte = (r * 256 + c4 * 8) ^ ((r & 7) << 4);
      *(uint2*)(Al + byte) = p;
    }
    __syncthreads();
    f32x4 acc[8];
#pragma unroll
    for (int ct = 0; ct < 8; ct++) acc[ct] = (f32x4){0.f, 0.f, 0.f, 0.f};
    int arow = w * 16 + (lane & 15);
#pragma unroll
    for (int ks = 0; ks < 4; ks++) {
      int abyte = (arow * 256 + ks * 64 + (lane >> 4) * 16) ^ ((arow & 7) << 4);
      short8v a = *(const short8v*)(Al + abyte);
#pragma unroll
      for (int ct = 0; ct < 8; ct++) {
        short8v bb = *(const short8v*)((const char*)Wl4 + ((ks * 8 + ct) * 64 + lane) * 16);
        acc[ct] = __builtin_amdgcn_mfma_f32_16x16x32_bf16(a, bb, acc[ct], 0, 0, 0);
      }
    }
#pragma unroll
    for (int j = 0; j < 4; j++) {
      int lr = w * 16 + ((lane >> 4) << 2) + j;
      int grow = trow0 + lr;
      if (grow < N_NODES) {
        float scale = sdinv[t * 64 + lr];
#pragma unroll
        for (int ct = 0; ct < 8; ct++) {
          x0b[(uint)grow * 128u + ct * 16 + (lane & 15)] =
              (unsigned short)bfrn(acc[ct][j] * scale);
        }
      }
    }
    __syncthreads();  // Al reuse guard
  }
}

// ---------------- prop, 128 bf16 feats, coefficient-free, 2 edges/wave ------------
// X is pre-scaled (x' = dinv * x); out = relu(dinv[node] * (sum x'[c] + x'[node])).

template <bool RELU>
__global__ __launch_bounds__(256) void prop128s_k(const uint2* __restrict__ X,  // bf16x4
                                                  uint2* __restrict__ Yb,       // bf16x4
                                                  const int* __restrict__ off,
                                                  const uint* __restrict__ cc,
                                                  const float* __restrict__ dinv) {
  int node = blockIdx.x * 4 + (threadIdx.x >> 6);
  if (node >= N_NODES) return;
  uint lane = threadIdx.x & 63u;
  uint sub = lane >> 5, o32 = lane & 31u;
  float di = dinv[node];
  uint2 s = X[(uint)node * 32u + o32];
  float4 acc = make_float4(0.f, 0.f, 0.f, 0.f);
  int e = off[node], e1 = off[node + 1];
  for (; e + 7 < e1; e += 8) {  // 4 pairs = 8 edges
    uint c[4];
    uint2 v[4];
#pragma unroll
    for (int j = 0; j < 4; j++) c[j] = cc[e + 2 * j + sub];
#pragma unroll
    for (int j = 0; j < 4; j++) v[j] = X[c[j] * 32u + o32];
#pragma unroll
    for (int j = 0; j < 4; j++) {
      acc.x += bflo(v[j].x);
      acc.y += bfhi(v[j].x);
      acc.z += bflo(v[j].y);
      acc.w += bfhi(v[j].y);
    }
  }
  for (; e + 1 < e1; e += 2) {
    uint c = cc[e + sub];
    uint2 v = X[c * 32u + o32];
    acc.x += bflo(v.x);
    acc.y += bfhi(v.x);
    acc.z += bflo(v.y);
    acc.w += bfhi(v.y);
  }
  if (e < e1 && sub == 0) {  // odd tail edge: half-wave only
    uint c = cc[e];
    uint2 v = X[c * 32u + o32];
    acc.x += bflo(v.x);
    acc.y += bfhi(v.x);
    acc.z += bflo(v.y);
    acc.w += bfhi(v.y);
  }
  acc.x += __shfl_xor(acc.x, 32);
  acc.y += __shfl_xor(acc.y, 32);
  acc.z += __shfl_xor(acc.z, 32);
  acc.w += __shfl_xor(acc.w, 32);
  acc.x = (acc.x + bflo(s.x)) * di;
  acc.y = (acc.y + bfhi(s.x)) * di;
  acc.z = (acc.z + bflo(s.y)) * di;
  acc.w = (acc.w + bfhi(s.y)) * di;
  if (RELU) {
    acc.x = fmaxf(acc.x, 0.f); acc.y = fmaxf(acc.y, 0.f);
    acc.z = fmaxf(acc.z, 0.f); acc.w = fmaxf(acc.w, 0.f);
  }
  if (sub == 0) {
    uint2 p;
    p.x = bfpack(acc.x, acc.y);
    p.y = bfpack(acc.z, acc.w);
    Yb[(uint)node * 32u + o32] = p;
  }
}

// ---------------- MFMA GEMM: t2b[64 x 64] = x1b[64 x 128] @ W2, dinv epilogue -----

__global__ __launch_bounds__(256) void mgemm64_k(const unsigned short* __restrict__ Ab16,
                                                 const unsigned short* __restrict__ Wp,
                                                 unsigned short* __restrict__ Cb,
                                                 const float* __restrict__ dinv) {
  __shared__ uint4 Al4[64 * 16];  // 16 KB: 64 rows x 128 bf16 (swizzled)
  __shared__ uint4 Wl4[64 * 16];  // 16 KB packed W2 fragments
  char* Al = (char*)Al4;
  int tid = threadIdx.x;
  int row0 = blockIdx.x * 64;
  for (int i = tid; i < 64 * 16; i += 256) Wl4[i] = ((const uint4*)Wp)[i];
  const uint4* Ab = (const uint4*)Ab16;
  for (int i = tid; i < 64 * 16; i += 256) {
    int r = i >> 4, c8 = i & 15;
    int gr = row0 + r;
    uint4 v = make_uint4(0, 0, 0, 0);
    if (gr < N_NODES) v = Ab[(uint)gr * 16u + c8];
    int byte = (r * 256 + c8 * 16) ^ ((r & 7) << 4);
    *(uint4*)(Al + byte) = v;
  }
  __syncthreads();
  int lane = tid & 63, w = tid >> 6;
  f32x4 acc[4];
#pragma unroll
  for (int ct = 0; ct < 4; ct++) acc[ct] = (f32x4){0.f, 0.f, 0.f, 0.f};
  int arow = w * 16 + (lane & 15);
#pragma unroll
  for (int ks = 0; ks < 4; ks++) {
    int abyte = (arow * 256 + ks * 64 + (lane >> 4) * 16) ^ ((arow & 7) << 4);
    short8v a = *(const short8v*)(Al + abyte);
#pragma unroll
    for (int ct = 0; ct < 4; ct++) {
      short8v bb = *(const short8v*)((const char*)Wl4 + ((ks * 4 + ct) * 64 + lane) * 16);
      acc[ct] = __builtin_amdgcn_mfma_f32_16x16x32_bf16(a, bb, acc[ct], 0, 0, 0);
    }
  }
#pragma unroll
  for (int j = 0; j < 4; j++) {
    int grow = row0 + w * 16 + ((lane >> 4) << 2) + j;
    if (grow < N_NODES) {
      float scale = dinv[grow];
#pragma unroll
      for (int ct = 0; ct < 4; ct++) {
        Cb[(uint)grow * 64u + ct * 16 + (lane & 15)] =
            (unsigned short)bfrn(acc[ct][j] * scale);
      }
    }
  }
}

// ---------------- prop, 64 bf16 feats, coefficient-free, fp32 out -----------------

__global__ __launch_bounds__(256) void prop64s_k(const uint* __restrict__ X,  // bf16x2
                                                 float2* __restrict__ Y,
                                                 const int* __restrict__ off,
                                                 const uint* __restrict__ cc,
                                                 const float* __restrict__ dinv) {
  int node = blockIdx.x * 4 + (threadIdx.x >> 6);
  if (node >= N_NODES) return;
  uint lane = threadIdx.x & 63u;
  uint sub = lane >> 5, o32 = lane & 31u;
  float di = dinv[node];
  uint s = X[(uint)node * 32u + o32];
  float2 acc = make_float2(0.f, 0.f);
  int e = off[node], e1 = off[node + 1];
  for (; e + 7 < e1; e += 8) {
    uint c[4];
    uint v[4];
#pragma unroll
    for (int j = 0; j < 4; j++) c[j] = cc[e + 2 * j + sub];
#pragma unroll
    for (int j = 0; j < 4; j++) v[j] = X[c[j] * 32u + o32];
#pragma unroll
    for (int j = 0; j < 4; j++) {
      acc.x += bflo(v[j]);
      acc.y += bfhi(v[j]);
    }
  }
  for (; e + 1 < e1; e += 2) {
    uint v = X[cc[e + sub] * 32u + o32];
    acc.x += bflo(v);
    acc.y += bfhi(v);
  }
  if (e < e1 && sub == 0) {
    uint v = X[cc[e] * 32u + o32];
    acc.x += bflo(v);
    acc.y += bfhi(v);
  }
  acc.x += __shfl_xor(acc.x, 32);
  acc.y += __shfl_xor(acc.y, 32);
  acc.x = (acc.x + bflo(s)) * di;
  acc.y = (acc.y + bfhi(s)) * di;
  if (sub == 0) Y[(uint)node * 32u + o32] = acc;
}

// ---------------- launch ----------------
// Pipeline (uses (PX)W == P(XW) and D^-1/2 factoring):
//   memset gcur; combo: binbuf bucket-sort + W01p/W2p packs
//   buckgemm: off/dinv/cc + x0b = bf16(dinv ⊙ (feat@W01))   [MFMA]
//   prop128s: x1b = bf16(relu(dinv ⊙ gather(x0b)))           (pure gather, high occ)
//   mgemm64:  t2b = bf16(dinv ⊙ (x1b @ W2))                  [MFMA]
//   prop64s:  out = dinv ⊙ gather(t2b)                        (fp32)

extern "C" void kernel_launch(void* const* d_in, const int* in_sizes, int n_in,
                              void* d_out, int out_size, void* d_ws, size_t ws_size,
                              hipStream_t stream) {
  const float* feat = (const float*)d_in[0];
  const int* ei = (const int*)d_in[1];  // int32 per harness contract
  const float* W0 = (const float*)d_in[2];
  const float* W1 = (const float*)d_in[3];
  const float* W2 = (const float*)d_in[4];
  float2* out = (float2*)d_out;

  char* ws = (char*)d_ws;
  unsigned short* x0b = (unsigned short*)ws; ws += (size_t)N_NODES * 128 * 2;  // 25.6 MB
  unsigned short* x1b = (unsigned short*)ws; ws += (size_t)N_NODES * 128 * 2;  // 25.6 MB
  unsigned short* t2b = (unsigned short*)ws; ws += (size_t)N_NODES * 64 * 2;   // 12.8 MB
  unsigned* binbuf = (unsigned*)ws;          ws += (size_t)NB * CAP * 4;       // 8.0 MB
  uint* cc = (uint*)ws;                      ws += (size_t)N_EDGES * 4;        // 6.4 MB
  float* dinv = (float*)ws;                  ws += (size_t)N_NODES * 4;
  int* off = (int*)ws;                       ws += (size_t)(N_NODES + 2) * 4;
  int* gcur = (int*)ws;                      ws += (size_t)NB * 4;
  unsigned short* W01p = (unsigned short*)ws; ws += 128 * 128 * 2;
  unsigned short* W2p = (unsigned short*)ws;  ws += 128 * 64 * 2;

  hipMemsetAsync(gcur, 0, (size_t)NB * 4, stream);
  combo_k<<<NBLK + 96, 256, 0, stream>>>(ei, gcur, binbuf, W0, W1, W2, W01p, W2p);
  buckgemm_k<<<NB, 256, 0, stream>>>(binbuf, gcur, feat, W01p, off, dinv, cc, x0b);
  prop128s_k<true><<<(N_NODES + 3) / 4, 256, 0, stream>>>((const uint2*)x0b, (uint2*)x1b,
                                                          off, cc, dinv);
  mgemm64_k<<<(N_NODES + 63) / 64, 256, 0, stream>>>(x1b, W2p, t2b, dinv);
  prop64s_k<<<(N_NODES + 3) / 4, 256, 0, stream>>>((const uint*)t2b, out, off, cc, dinv);
}

// Round 12
// 193.783 us; speedup vs baseline: 1.1892x; 1.0101x over previous
//
#include <hip/hip_runtime.h>

#define N_NODES 100000
#define N_EDGES 1600000
#define NB 391            // ceil(N_NODES/256) row-buckets of 256 rows
#define NBLK 256          // blocks for binning pass
#define CHUNK 6250        // ceil(N_EDGES/NBLK)
#define CAP 5120          // per-bucket binbuf capacity (mean 4096, sigma 64)

typedef unsigned int uint;
typedef __attribute__((ext_vector_type(8))) short short8v;  // 8 bf16 (4 VGPRs)
typedef __attribute__((ext_vector_type(4))) float f32x4;

// ---------------- bf16 helpers ----------------

__device__ __forceinline__ uint bfrn(float x) {  // fp32 -> bf16 bits (RN)
  uint u = __float_as_uint(x);
  u += 0x7fffu + ((u >> 16) & 1u);
  return u >> 16;
}
__device__ __forceinline__ uint bfpack(float a, float b) {
  return bfrn(a) | (bfrn(b) << 16);
}
__device__ __forceinline__ float bflo(uint u) { return __uint_as_float(u << 16); }
__device__ __forceinline__ float bfhi(uint u) { return __uint_as_float(u & 0xffff0000u); }

// ---------------- kernel A: binning (blocks 0-255) + weight packs (256-351) -------
// gcur zero-init by hipMemsetAsync; reservation slot = i*CAP + atomicAdd(gcur[i],c).
// Packed B-fragment index for element (k,f), NCT=FOUT/16:
//   ks=k>>5, j=k&7, lq=(k>>3)&3, lane=(lq<<4)|(f&15), ct=f>>4
//   idx = ((ks*NCT + ct)*64 + lane)*8 + j

__global__ __launch_bounds__(256) void combo_k(const int* __restrict__ ei,
                                               int* __restrict__ gcur,
                                               unsigned* __restrict__ binbuf,
                                               const float* __restrict__ W0,
                                               const float* __restrict__ W1,
                                               const float* __restrict__ W2,
                                               unsigned short* __restrict__ W01p,
                                               unsigned short* __restrict__ W2p) {
  int b = blockIdx.x;
  if (b < NBLK) {
    __shared__ int lh[NB];
    for (int i = threadIdx.x; i < NB; i += 256) lh[i] = 0;
    __syncthreads();
    int ebeg = b * CHUNK, e1 = min(ebeg + CHUNK, N_EDGES);
    for (int e = ebeg + threadIdx.x; e < e1; e += 256) {
      atomicAdd(&lh[ei[e] >> 8], 1);
    }
    __syncthreads();
    for (int i = threadIdx.x; i < NB; i += 256) {
      int c = lh[i];
      lh[i] = c ? (i * CAP + atomicAdd(&gcur[i], c)) : 0;
    }
    __syncthreads();
    for (int e = ebeg + threadIdx.x; e < e1; e += 256) {
      int r = ei[e];
      int c = ei[N_EDGES + e];
      int p = atomicAdd(&lh[r >> 8], 1);
      binbuf[p] = ((unsigned)(r & 255) << 24) | (unsigned)c;  // c < 2^17 fits
    }
  } else if (b < NBLK + 64) {
    int g = (b - NBLK) * 256 + threadIdx.x;  // 16384: W01 = W0@W1
    int k = g >> 7, f = g & 127;
    float s = 0.f;
    for (int kk = 0; kk < 128; kk++) s = fmaf(W0[k * 128 + kk], W1[kk * 128 + f], s);
    int ks = k >> 5, j = k & 7, lq = (k >> 3) & 3;
    int lane = (lq << 4) | (f & 15), ct = f >> 4;
    W01p[((ks * 8 + ct) * 64 + lane) * 8 + j] = (unsigned short)bfrn(s);
  } else {
    int g = (b - NBLK - 64) * 256 + threadIdx.x;  // 8192: W2
    int k = g >> 6, f = g & 63;
    int ks = k >> 5, j = k & 7, lq = (k >> 3) & 3;
    int lane = (lq << 4) | (f & 15), ct = f >> 4;
    W2p[((ks * 4 + ct) * 64 + lane) * 8 + j] = (unsigned short)bfrn(W2[k * 64 + f]);
  }
}

// ---------------- kernel B: per-bucket CSR build only (391 short blocks) ----------

__global__ __launch_bounds__(256) void buckoff_k(const unsigned* __restrict__ binbuf,
                                                 const int* __restrict__ gcur,
                                                 int* __restrict__ off,
                                                 float* __restrict__ dinv,
                                                 uint* __restrict__ cc) {
  __shared__ int cnt[256];
  __shared__ int sc[256];
  __shared__ int sbase_s;
  int k = blockIdx.x, row0n = k << 8, tid = threadIdx.x;
  if (tid < 64) {  // sbase = sum_{j<k} count_j
    int s = 0;
    for (int j = tid; j < k; j += 64) s += gcur[j];
#pragma unroll
    for (int d = 32; d; d >>= 1) s += __shfl_xor(s, d);
    if (tid == 0) sbase_s = s;
  }
  cnt[tid] = 0;
  __syncthreads();
  int n = gcur[k];
  int sb = k * CAP;
  for (int t = tid; t < n; t += 256) atomicAdd(&cnt[binbuf[sb + t] >> 24], 1);
  __syncthreads();
  int v = cnt[tid];
  sc[tid] = v;
  __syncthreads();
  for (int d = 1; d < 256; d <<= 1) {
    int t = (tid >= d) ? sc[tid - d] : 0;
    __syncthreads();
    sc[tid] += t;
    __syncthreads();
  }
  int row = row0n + tid;
  int mystart = sbase_s + sc[tid] - v;
  if (row < N_NODES) {
    off[row] = mystart;
    dinv[row] = rsqrtf((float)v + 1.0f);  // +1 = self-loop
  }
  if (k == NB - 1 && tid == 0) off[N_NODES] = N_EDGES;
  __syncthreads();
  cnt[tid] = mystart;  // reuse as placement cursor
  __syncthreads();
  for (int t = tid; t < n; t += 256) {
    unsigned u = binbuf[sb + t];
    int slot = atomicAdd(&cnt[u >> 24], 1);
    cc[slot] = u & 0xFFFFFFu;
  }
}

// ---------------- MFMA GEMM 128->128: x0b = bf16(dinv ⊙ (feat @ W01)) -------------

__global__ __launch_bounds__(256) void mgemm128_k(const float* __restrict__ feat,
                                                  const unsigned short* __restrict__ Wp,
                                                  unsigned short* __restrict__ Cb,
                                                  const float* __restrict__ dinv) {
  __shared__ uint4 Al4[64 * 16];    // 16 KB A tile (swizzled bf16)
  __shared__ uint4 Wl4[128 * 16];   // 32 KB packed W01 fragments
  char* Al = (char*)Al4;
  int tid = threadIdx.x;
  int row0 = blockIdx.x * 64;
  for (int i = tid; i < 128 * 16; i += 256) Wl4[i] = ((const uint4*)Wp)[i];
  const float4* Af = (const float4*)feat;
  for (int i = tid; i < 64 * 32; i += 256) {
    int r = i >> 5, c4 = i & 31;
    int gr = row0 + r;
    float4 vv = make_float4(0.f, 0.f, 0.f, 0.f);
    if (gr < N_NODES) vv = Af[(uint)gr * 32u + c4];
    uint2 p;
    p.x = bfpack(vv.x, vv.y);
    p.y = bfpack(vv.z, vv.w);
    int byte = (r * 256 + c4 * 8) ^ ((r & 7) << 4);
    *(uint2*)(Al + byte) = p;
  }
  __syncthreads();
  int lane = tid & 63, w = tid >> 6;
  f32x4 acc[8];
#pragma unroll
  for (int ct = 0; ct < 8; ct++) acc[ct] = (f32x4){0.f, 0.f, 0.f, 0.f};
  int arow = w * 16 + (lane & 15);
#pragma unroll
  for (int ks = 0; ks < 4; ks++) {
    int abyte = (arow * 256 + ks * 64 + (lane >> 4) * 16) ^ ((arow & 7) << 4);
    short8v a = *(const short8v*)(Al + abyte);
#pragma unroll
    for (int ct = 0; ct < 8; ct++) {
      short8v bb = *(const short8v*)((const char*)Wl4 + ((ks * 8 + ct) * 64 + lane) * 16);
      acc[ct] = __builtin_amdgcn_mfma_f32_16x16x32_bf16(a, bb, acc[ct], 0, 0, 0);
    }
  }
#pragma unroll
  for (int j = 0; j < 4; j++) {
    int grow = row0 + w * 16 + ((lane >> 4) << 2) + j;
    if (grow < N_NODES) {
      float scale = dinv[grow];
#pragma unroll
      for (int ct = 0; ct < 8; ct++) {
        Cb[(uint)grow * 128u + ct * 16 + (lane & 15)] =
            (unsigned short)bfrn(acc[ct][j] * scale);
      }
    }
  }
}

// ---------------- prop, 128 bf16 feats, 4 edges/wave (16 lanes x uint4 each) ------
// X pre-scaled (x' = dinv*x). grp = lane>>4 picks edge of the quad; o16 = lane&15
// picks 8 feats (16B). Quads merged via shfl_xor 16 then 32.

template <bool RELU>
__global__ __launch_bounds__(256) void prop128q_k(const uint4* __restrict__ X4,  // bf16x8
                                                  uint4* __restrict__ Yb4,       // bf16x8
                                                  const int* __restrict__ off,
                                                  const uint* __restrict__ cc,
                                                  const float* __restrict__ dinv) {
  int node = blockIdx.x * 4 + (threadIdx.x >> 6);
  if (node >= N_NODES) return;
  uint lane = threadIdx.x & 63u;
  uint grp = lane >> 4, o16 = lane & 15u;
  float di = dinv[node];
  uint4 s = X4[(uint)node * 16u + o16];
  float a0 = 0.f, a1 = 0.f, a2 = 0.f, a3 = 0.f, a4 = 0.f, a5 = 0.f, a6 = 0.f, a7 = 0.f;
  int e = off[node], e1 = off[node + 1];
  for (; e + 7 < e1; e += 8) {  // 2 quads = 8 edges
    uint c0 = cc[e + grp], c1 = cc[e + 4 + grp];
    uint4 v0 = X4[c0 * 16u + o16];
    uint4 v1 = X4[c1 * 16u + o16];
    a0 += bflo(v0.x) + bflo(v1.x);
    a1 += bfhi(v0.x) + bfhi(v1.x);
    a2 += bflo(v0.y) + bflo(v1.y);
    a3 += bfhi(v0.y) + bfhi(v1.y);
    a4 += bflo(v0.z) + bflo(v1.z);
    a5 += bfhi(v0.z) + bfhi(v1.z);
    a6 += bflo(v0.w) + bflo(v1.w);
    a7 += bfhi(v0.w) + bfhi(v1.w);
  }
  for (; e + 3 < e1; e += 4) {  // one quad
    uint c0 = cc[e + grp];
    uint4 v0 = X4[c0 * 16u + o16];
    a0 += bflo(v0.x); a1 += bfhi(v0.x);
    a2 += bflo(v0.y); a3 += bfhi(v0.y);
    a4 += bflo(v0.z); a5 += bfhi(v0.z);
    a6 += bflo(v0.w); a7 += bfhi(v0.w);
  }
  if (e + (int)grp < e1) {  // tail 1..3 edges: group-masked
    uint c0 = cc[e + grp];
    uint4 v0 = X4[c0 * 16u + o16];
    a0 += bflo(v0.x); a1 += bfhi(v0.x);
    a2 += bflo(v0.y); a3 += bfhi(v0.y);
    a4 += bflo(v0.z); a5 += bfhi(v0.z);
    a6 += bflo(v0.w); a7 += bfhi(v0.w);
  }
  a0 += __shfl_xor(a0, 16); a1 += __shfl_xor(a1, 16);
  a2 += __shfl_xor(a2, 16); a3 += __shfl_xor(a3, 16);
  a4 += __shfl_xor(a4, 16); a5 += __shfl_xor(a5, 16);
  a6 += __shfl_xor(a6, 16); a7 += __shfl_xor(a7, 16);
  a0 += __shfl_xor(a0, 32); a1 += __shfl_xor(a1, 32);
  a2 += __shfl_xor(a2, 32); a3 += __shfl_xor(a3, 32);
  a4 += __shfl_xor(a4, 32); a5 += __shfl_xor(a5, 32);
  a6 += __shfl_xor(a6, 32); a7 += __shfl_xor(a7, 32);
  a0 = (a0 + bflo(s.x)) * di; a1 = (a1 + bfhi(s.x)) * di;
  a2 = (a2 + bflo(s.y)) * di; a3 = (a3 + bfhi(s.y)) * di;
  a4 = (a4 + bflo(s.z)) * di; a5 = (a5 + bfhi(s.z)) * di;
  a6 = (a6 + bflo(s.w)) * di; a7 = (a7 + bfhi(s.w)) * di;
  if (RELU) {
    a0 = fmaxf(a0, 0.f); a1 = fmaxf(a1, 0.f); a2 = fmaxf(a2, 0.f); a3 = fmaxf(a3, 0.f);
    a4 = fmaxf(a4, 0.f); a5 = fmaxf(a5, 0.f); a6 = fmaxf(a6, 0.f); a7 = fmaxf(a7, 0.f);
  }
  if (lane < 16) {
    uint4 p;
    p.x = bfpack(a0, a1);
    p.y = bfpack(a2, a3);
    p.z = bfpack(a4, a5);
    p.w = bfpack(a6, a7);
    Yb4[(uint)node * 16u + o16] = p;
  }
}

// ---------------- MFMA GEMM: t2b[64 x 64] = x1b[64 x 128] @ W2, dinv epilogue -----

__global__ __launch_bounds__(256) void mgemm64_k(const unsigned short* __restrict__ Ab16,
                                                 const unsigned short* __restrict__ Wp,
                                                 unsigned short* __restrict__ Cb,
                                                 const float* __restrict__ dinv) {
  __shared__ uint4 Al4[64 * 16];  // 16 KB: 64 rows x 128 bf16 (swizzled)
  __shared__ uint4 Wl4[64 * 16];  // 16 KB packed W2 fragments
  char* Al = (char*)Al4;
  int tid = threadIdx.x;
  int row0 = blockIdx.x * 64;
  for (int i = tid; i < 64 * 16; i += 256) Wl4[i] = ((const uint4*)Wp)[i];
  const uint4* Ab = (const uint4*)Ab16;
  for (int i = tid; i < 64 * 16; i += 256) {
    int r = i >> 4, c8 = i & 15;
    int gr = row0 + r;
    uint4 v = make_uint4(0, 0, 0, 0);
    if (gr < N_NODES) v = Ab[(uint)gr * 16u + c8];
    int byte = (r * 256 + c8 * 16) ^ ((r & 7) << 4);
    *(uint4*)(Al + byte) = v;
  }
  __syncthreads();
  int lane = tid & 63, w = tid >> 6;
  f32x4 acc[4];
#pragma unroll
  for (int ct = 0; ct < 4; ct++) acc[ct] = (f32x4){0.f, 0.f, 0.f, 0.f};
  int arow = w * 16 + (lane & 15);
#pragma unroll
  for (int ks = 0; ks < 4; ks++) {
    int abyte = (arow * 256 + ks * 64 + (lane >> 4) * 16) ^ ((arow & 7) << 4);
    short8v a = *(const short8v*)(Al + abyte);
#pragma unroll
    for (int ct = 0; ct < 4; ct++) {
      short8v bb = *(const short8v*)((const char*)Wl4 + ((ks * 4 + ct) * 64 + lane) * 16);
      acc[ct] = __builtin_amdgcn_mfma_f32_16x16x32_bf16(a, bb, acc[ct], 0, 0, 0);
    }
  }
#pragma unroll
  for (int j = 0; j < 4; j++) {
    int grow = row0 + w * 16 + ((lane >> 4) << 2) + j;
    if (grow < N_NODES) {
      float scale = dinv[grow];
#pragma unroll
      for (int ct = 0; ct < 4; ct++) {
        Cb[(uint)grow * 64u + ct * 16 + (lane & 15)] =
            (unsigned short)bfrn(acc[ct][j] * scale);
      }
    }
  }
}

// ---------------- prop, 64 bf16 feats, 4 edges/wave (16 lanes x uint2), fp32 out ---

__global__ __launch_bounds__(256) void prop64q_k(const uint2* __restrict__ X2,  // bf16x4
                                                 float4* __restrict__ Y4,
                                                 const int* __restrict__ off,
                                                 const uint* __restrict__ cc,
                                                 const float* __restrict__ dinv) {
  int node = blockIdx.x * 4 + (threadIdx.x >> 6);
  if (node >= N_NODES) return;
  uint lane = threadIdx.x & 63u;
  uint grp = lane >> 4, o16 = lane & 15u;
  float di = dinv[node];
  uint2 s = X2[(uint)node * 16u + o16];
  float a0 = 0.f, a1 = 0.f, a2 = 0.f, a3 = 0.f;
  int e = off[node], e1 = off[node + 1];
  for (; e + 7 < e1; e += 8) {
    uint c0 = cc[e + grp], c1 = cc[e + 4 + grp];
    uint2 v0 = X2[c0 * 16u + o16];
    uint2 v1 = X2[c1 * 16u + o16];
    a0 += bflo(v0.x) + bflo(v1.x);
    a1 += bfhi(v0.x) + bfhi(v1.x);
    a2 += bflo(v0.y) + bflo(v1.y);
    a3 += bfhi(v0.y) + bfhi(v1.y);
  }
  for (; e + 3 < e1; e += 4) {
    uint c0 = cc[e + grp];
    uint2 v0 = X2[c0 * 16u + o16];
    a0 += bflo(v0.x); a1 += bfhi(v0.x);
    a2 += bflo(v0.y); a3 += bfhi(v0.y);
  }
  if (e + (int)grp < e1) {
    uint c0 = cc[e + grp];
    uint2 v0 = X2[c0 * 16u + o16];
    a0 += bflo(v0.x); a1 += bfhi(v0.x);
    a2 += bflo(v0.y); a3 += bfhi(v0.y);
  }
  a0 += __shfl_xor(a0, 16); a1 += __shfl_xor(a1, 16);
  a2 += __shfl_xor(a2, 16); a3 += __shfl_xor(a3, 16);
  a0 += __shfl_xor(a0, 32); a1 += __shfl_xor(a1, 32);
  a2 += __shfl_xor(a2, 32); a3 += __shfl_xor(a3, 32);
  a0 = (a0 + bflo(s.x)) * di;
  a1 = (a1 + bfhi(s.x)) * di;
  a2 = (a2 + bflo(s.y)) * di;
  a3 = (a3 + bfhi(s.y)) * di;
  if (lane < 16) {
    float4 o;
    o.x = a0; o.y = a1; o.z = a2; o.w = a3;
    Y4[(uint)node * 16u + o16] = o;
  }
}

// ---------------- launch ----------------
// Pipeline (uses (PX)W == P(XW) and D^-1/2 factoring):
//   memset gcur; combo: binbuf bucket-sort + W01p/W2p packs
//   buckoff:  off/dinv/cc (CSR)
//   mgemm128: x0b = bf16(dinv ⊙ (feat@W01))    [MFMA, full occupancy]
//   prop128q: x1b = bf16(relu(dinv ⊙ gather(x0b)))
//   mgemm64:  t2b = bf16(dinv ⊙ (x1b @ W2))    [MFMA]
//   prop64q:  out = dinv ⊙ gather(t2b)          (fp32)

extern "C" void kernel_launch(void* const* d_in, const int* in_sizes, int n_in,
                              void* d_out, int out_size, void* d_ws, size_t ws_size,
                              hipStream_t stream) {
  const float* feat = (const float*)d_in[0];
  const int* ei = (const int*)d_in[1];  // int32 per harness contract
  const float* W0 = (const float*)d_in[2];
  const float* W1 = (const float*)d_in[3];
  const float* W2 = (const float*)d_in[4];
  float4* out = (float4*)d_out;

  char* ws = (char*)d_ws;
  unsigned short* x0b = (unsigned short*)ws; ws += (size_t)N_NODES * 128 * 2;  // 25.6 MB
  unsigned short* x1b = (unsigned short*)ws; ws += (size_t)N_NODES * 128 * 2;  // 25.6 MB
  unsigned short* t2b = (unsigned short*)ws; ws += (size_t)N_NODES * 64 * 2;   // 12.8 MB
  unsigned* binbuf = (unsigned*)ws;          ws += (size_t)NB * CAP * 4;       // 8.0 MB
  uint* cc = (uint*)ws;                      ws += (size_t)N_EDGES * 4;        // 6.4 MB
  float* dinv = (float*)ws;                  ws += (size_t)N_NODES * 4;
  int* off = (int*)ws;                       ws += (size_t)(N_NODES + 2) * 4;
  int* gcur = (int*)ws;                      ws += (size_t)NB * 4;
  unsigned short* W01p = (unsigned short*)ws; ws += 128 * 128 * 2;
  unsigned short* W2p = (unsigned short*)ws;  ws += 128 * 64 * 2;

  hipMemsetAsync(gcur, 0, (size_t)NB * 4, stream);
  combo_k<<<NBLK + 96, 256, 0, stream>>>(ei, gcur, binbuf, W0, W1, W2, W01p, W2p);
  buckoff_k<<<NB, 256, 0, stream>>>(binbuf, gcur, off, dinv, cc);
  mgemm128_k<<<(N_NODES + 63) / 64, 256, 0, stream>>>(feat, W01p, x0b, dinv);
  prop128q_k<true><<<(N_NODES + 3) / 4, 256, 0, stream>>>((const uint4*)x0b, (uint4*)x1b,
                                                          off, cc, dinv);
  mgemm64_k<<<(N_NODES + 63) / 64, 256, 0, stream>>>(x1b, W2p, t2b, dinv);
  prop64q_k<<<(N_NODES + 3) / 4, 256, 0, stream>>>((const uint2*)t2b, out, off, cc, dinv);
}

// Round 13
// 187.020 us; speedup vs baseline: 1.2322x; 1.0362x over previous
//
#include <hip/hip_runtime.h>

#define N_NODES 100000
#define N_EDGES 1600000
#define NB 391            // ceil(N_NODES/256) row-buckets of 256 rows
#define NBLK 256          // blocks for binning pass
#define CHUNK 6250        // ceil(N_EDGES/NBLK)
#define CAP 5120          // per-bucket binbuf capacity (mean 4096, sigma 64)

typedef unsigned int uint;
typedef __attribute__((ext_vector_type(8))) short short8v;  // 8 bf16 (4 VGPRs)
typedef __attribute__((ext_vector_type(4))) float f32x4;

// ---------------- bf16 helpers ----------------

__device__ __forceinline__ uint bfrn(float x) {  // fp32 -> bf16 bits (RN)
  uint u = __float_as_uint(x);
  u += 0x7fffu + ((u >> 16) & 1u);
  return u >> 16;
}
__device__ __forceinline__ uint bfpack(float a, float b) {
  return bfrn(a) | (bfrn(b) << 16);
}
__device__ __forceinline__ float bflo(uint u) { return __uint_as_float(u << 16); }
__device__ __forceinline__ float bfhi(uint u) { return __uint_as_float(u & 0xffff0000u); }

// ---------------- kernel A: binning (blocks 0-255) + weight packs (256-351) -------
// gcur zero-init by hipMemsetAsync; reservation slot = i*CAP + atomicAdd(gcur[i],c).
// Packed B-fragment index for element (k,f), NCT=FOUT/16:
//   ks=k>>5, j=k&7, lq=(k>>3)&3, lane=(lq<<4)|(f&15), ct=f>>4
//   idx = ((ks*NCT + ct)*64 + lane)*8 + j

__global__ __launch_bounds__(256) void combo_k(const int* __restrict__ ei,
                                               int* __restrict__ gcur,
                                               unsigned* __restrict__ binbuf,
                                               const float* __restrict__ W0,
                                               const float* __restrict__ W1,
                                               const float* __restrict__ W2,
                                               unsigned short* __restrict__ W01p,
                                               unsigned short* __restrict__ W2p) {
  int b = blockIdx.x;
  if (b < NBLK) {
    __shared__ int lh[NB];
    for (int i = threadIdx.x; i < NB; i += 256) lh[i] = 0;
    __syncthreads();
    int ebeg = b * CHUNK, e1 = min(ebeg + CHUNK, N_EDGES);
    for (int e = ebeg + threadIdx.x; e < e1; e += 256) {
      atomicAdd(&lh[ei[e] >> 8], 1);
    }
    __syncthreads();
    for (int i = threadIdx.x; i < NB; i += 256) {
      int c = lh[i];
      lh[i] = c ? (i * CAP + atomicAdd(&gcur[i], c)) : 0;
    }
    __syncthreads();
    for (int e = ebeg + threadIdx.x; e < e1; e += 256) {
      int r = ei[e];
      int c = ei[N_EDGES + e];
      int p = atomicAdd(&lh[r >> 8], 1);
      binbuf[p] = ((unsigned)(r & 255) << 24) | (unsigned)c;  // c < 2^17 fits
    }
  } else if (b < NBLK + 64) {
    int g = (b - NBLK) * 256 + threadIdx.x;  // 16384: W01 = W0@W1
    int k = g >> 7, f = g & 127;
    float s = 0.f;
    for (int kk = 0; kk < 128; kk++) s = fmaf(W0[k * 128 + kk], W1[kk * 128 + f], s);
    int ks = k >> 5, j = k & 7, lq = (k >> 3) & 3;
    int lane = (lq << 4) | (f & 15), ct = f >> 4;
    W01p[((ks * 8 + ct) * 64 + lane) * 8 + j] = (unsigned short)bfrn(s);
  } else {
    int g = (b - NBLK - 64) * 256 + threadIdx.x;  // 8192: W2
    int k = g >> 6, f = g & 63;
    int ks = k >> 5, j = k & 7, lq = (k >> 3) & 3;
    int lane = (lq << 4) | (f & 15), ct = f >> 4;
    W2p[((ks * 4 + ct) * 64 + lane) * 8 + j] = (unsigned short)bfrn(W2[k * 64 + f]);
  }
}

// ---------------- kernel B: per-bucket CSR build only (391 short blocks) ----------

__global__ __launch_bounds__(256) void buckoff_k(const unsigned* __restrict__ binbuf,
                                                 const int* __restrict__ gcur,
                                                 int* __restrict__ off,
                                                 float* __restrict__ dinv,
                                                 uint* __restrict__ cc) {
  __shared__ int cnt[256];
  __shared__ int sc[256];
  __shared__ int sbase_s;
  int k = blockIdx.x, row0n = k << 8, tid = threadIdx.x;
  if (tid < 64) {  // sbase = sum_{j<k} count_j
    int s = 0;
    for (int j = tid; j < k; j += 64) s += gcur[j];
#pragma unroll
    for (int d = 32; d; d >>= 1) s += __shfl_xor(s, d);
    if (tid == 0) sbase_s = s;
  }
  cnt[tid] = 0;
  __syncthreads();
  int n = gcur[k];
  int sb = k * CAP;
  for (int t = tid; t < n; t += 256) atomicAdd(&cnt[binbuf[sb + t] >> 24], 1);
  __syncthreads();
  int v = cnt[tid];
  sc[tid] = v;
  __syncthreads();
  for (int d = 1; d < 256; d <<= 1) {
    int t = (tid >= d) ? sc[tid - d] : 0;
    __syncthreads();
    sc[tid] += t;
    __syncthreads();
  }
  int row = row0n + tid;
  int mystart = sbase_s + sc[tid] - v;
  if (row < N_NODES) {
    off[row] = mystart;
    dinv[row] = rsqrtf((float)v + 1.0f);  // +1 = self-loop
  }
  if (k == NB - 1 && tid == 0) off[N_NODES] = N_EDGES;
  __syncthreads();
  cnt[tid] = mystart;  // reuse as placement cursor
  __syncthreads();
  for (int t = tid; t < n; t += 256) {
    unsigned u = binbuf[sb + t];
    int slot = atomicAdd(&cnt[u >> 24], 1);
    cc[slot] = u & 0xFFFFFFu;
  }
}

// ---------------- MFMA GEMM 128->128: x0b = bf16(dinv ⊙ (feat @ W01)) -------------

__global__ __launch_bounds__(256) void mgemm128_k(const float* __restrict__ feat,
                                                  const unsigned short* __restrict__ Wp,
                                                  unsigned short* __restrict__ Cb,
                                                  const float* __restrict__ dinv) {
  __shared__ uint4 Al4[64 * 16];    // 16 KB A tile (swizzled bf16)
  __shared__ uint4 Wl4[128 * 16];   // 32 KB packed W01 fragments
  char* Al = (char*)Al4;
  int tid = threadIdx.x;
  int row0 = blockIdx.x * 64;
  for (int i = tid; i < 128 * 16; i += 256) Wl4[i] = ((const uint4*)Wp)[i];
  const float4* Af = (const float4*)feat;
  for (int i = tid; i < 64 * 32; i += 256) {
    int r = i >> 5, c4 = i & 31;
    int gr = row0 + r;
    float4 vv = make_float4(0.f, 0.f, 0.f, 0.f);
    if (gr < N_NODES) vv = Af[(uint)gr * 32u + c4];
    uint2 p;
    p.x = bfpack(vv.x, vv.y);
    p.y = bfpack(vv.z, vv.w);
    int byte = (r * 256 + c4 * 8) ^ ((r & 7) << 4);
    *(uint2*)(Al + byte) = p;
  }
  __syncthreads();
  int lane = tid & 63, w = tid >> 6;
  f32x4 acc[8];
#pragma unroll
  for (int ct = 0; ct < 8; ct++) acc[ct] = (f32x4){0.f, 0.f, 0.f, 0.f};
  int arow = w * 16 + (lane & 15);
#pragma unroll
  for (int ks = 0; ks < 4; ks++) {
    int abyte = (arow * 256 + ks * 64 + (lane >> 4) * 16) ^ ((arow & 7) << 4);
    short8v a = *(const short8v*)(Al + abyte);
#pragma unroll
    for (int ct = 0; ct < 8; ct++) {
      short8v bb = *(const short8v*)((const char*)Wl4 + ((ks * 8 + ct) * 64 + lane) * 16);
      acc[ct] = __builtin_amdgcn_mfma_f32_16x16x32_bf16(a, bb, acc[ct], 0, 0, 0);
    }
  }
#pragma unroll
  for (int j = 0; j < 4; j++) {
    int grow = row0 + w * 16 + ((lane >> 4) << 2) + j;
    if (grow < N_NODES) {
      float scale = dinv[grow];
#pragma unroll
      for (int ct = 0; ct < 8; ct++) {
        Cb[(uint)grow * 128u + ct * 16 + (lane & 15)] =
            (unsigned short)bfrn(acc[ct][j] * scale);
      }
    }
  }
}

// ---------------- prop, 128 bf16 feats, 4 edges/wave-load, 16-edge deep loop ------
// X pre-scaled (x' = dinv*x). grp = lane>>4 picks edge; o16 = lane&15 picks 8 feats.

template <bool RELU>
__global__ __launch_bounds__(256) void prop128q_k(const uint4* __restrict__ X4,  // bf16x8
                                                  uint4* __restrict__ Yb4,       // bf16x8
                                                  const int* __restrict__ off,
                                                  const uint* __restrict__ cc,
                                                  const float* __restrict__ dinv) {
  int node = blockIdx.x * 4 + (threadIdx.x >> 6);
  if (node >= N_NODES) return;
  uint lane = threadIdx.x & 63u;
  uint grp = lane >> 4, o16 = lane & 15u;
  float di = dinv[node];
  uint4 s = X4[(uint)node * 16u + o16];
  float a0 = 0.f, a1 = 0.f, a2 = 0.f, a3 = 0.f, a4 = 0.f, a5 = 0.f, a6 = 0.f, a7 = 0.f;
  int e = off[node], e1 = off[node + 1];
  for (; e + 15 < e1; e += 16) {  // 4 quads = 16 edges, 4 row-loads in flight
    uint c0 = cc[e + grp], c1 = cc[e + 4 + grp], c2 = cc[e + 8 + grp], c3 = cc[e + 12 + grp];
    uint4 v0 = X4[c0 * 16u + o16];
    uint4 v1 = X4[c1 * 16u + o16];
    uint4 v2 = X4[c2 * 16u + o16];
    uint4 v3 = X4[c3 * 16u + o16];
    a0 += bflo(v0.x) + bflo(v1.x) + bflo(v2.x) + bflo(v3.x);
    a1 += bfhi(v0.x) + bfhi(v1.x) + bfhi(v2.x) + bfhi(v3.x);
    a2 += bflo(v0.y) + bflo(v1.y) + bflo(v2.y) + bflo(v3.y);
    a3 += bfhi(v0.y) + bfhi(v1.y) + bfhi(v2.y) + bfhi(v3.y);
    a4 += bflo(v0.z) + bflo(v1.z) + bflo(v2.z) + bflo(v3.z);
    a5 += bfhi(v0.z) + bfhi(v1.z) + bfhi(v2.z) + bfhi(v3.z);
    a6 += bflo(v0.w) + bflo(v1.w) + bflo(v2.w) + bflo(v3.w);
    a7 += bfhi(v0.w) + bfhi(v1.w) + bfhi(v2.w) + bfhi(v3.w);
  }
  for (; e + 7 < e1; e += 8) {  // 2 quads
    uint c0 = cc[e + grp], c1 = cc[e + 4 + grp];
    uint4 v0 = X4[c0 * 16u + o16];
    uint4 v1 = X4[c1 * 16u + o16];
    a0 += bflo(v0.x) + bflo(v1.x);
    a1 += bfhi(v0.x) + bfhi(v1.x);
    a2 += bflo(v0.y) + bflo(v1.y);
    a3 += bfhi(v0.y) + bfhi(v1.y);
    a4 += bflo(v0.z) + bflo(v1.z);
    a5 += bfhi(v0.z) + bfhi(v1.z);
    a6 += bflo(v0.w) + bflo(v1.w);
    a7 += bfhi(v0.w) + bfhi(v1.w);
  }
  for (; e + 3 < e1; e += 4) {  // one quad
    uint c0 = cc[e + grp];
    uint4 v0 = X4[c0 * 16u + o16];
    a0 += bflo(v0.x); a1 += bfhi(v0.x);
    a2 += bflo(v0.y); a3 += bfhi(v0.y);
    a4 += bflo(v0.z); a5 += bfhi(v0.z);
    a6 += bflo(v0.w); a7 += bfhi(v0.w);
  }
  if (e + (int)grp < e1) {  // tail 1..3 edges: group-masked
    uint c0 = cc[e + grp];
    uint4 v0 = X4[c0 * 16u + o16];
    a0 += bflo(v0.x); a1 += bfhi(v0.x);
    a2 += bflo(v0.y); a3 += bfhi(v0.y);
    a4 += bflo(v0.z); a5 += bfhi(v0.z);
    a6 += bflo(v0.w); a7 += bfhi(v0.w);
  }
  a0 += __shfl_xor(a0, 16); a1 += __shfl_xor(a1, 16);
  a2 += __shfl_xor(a2, 16); a3 += __shfl_xor(a3, 16);
  a4 += __shfl_xor(a4, 16); a5 += __shfl_xor(a5, 16);
  a6 += __shfl_xor(a6, 16); a7 += __shfl_xor(a7, 16);
  a0 += __shfl_xor(a0, 32); a1 += __shfl_xor(a1, 32);
  a2 += __shfl_xor(a2, 32); a3 += __shfl_xor(a3, 32);
  a4 += __shfl_xor(a4, 32); a5 += __shfl_xor(a5, 32);
  a6 += __shfl_xor(a6, 32); a7 += __shfl_xor(a7, 32);
  a0 = (a0 + bflo(s.x)) * di; a1 = (a1 + bfhi(s.x)) * di;
  a2 = (a2 + bflo(s.y)) * di; a3 = (a3 + bfhi(s.y)) * di;
  a4 = (a4 + bflo(s.z)) * di; a5 = (a5 + bfhi(s.z)) * di;
  a6 = (a6 + bflo(s.w)) * di; a7 = (a7 + bfhi(s.w)) * di;
  if (RELU) {
    a0 = fmaxf(a0, 0.f); a1 = fmaxf(a1, 0.f); a2 = fmaxf(a2, 0.f); a3 = fmaxf(a3, 0.f);
    a4 = fmaxf(a4, 0.f); a5 = fmaxf(a5, 0.f); a6 = fmaxf(a6, 0.f); a7 = fmaxf(a7, 0.f);
  }
  if (lane < 16) {
    uint4 p;
    p.x = bfpack(a0, a1);
    p.y = bfpack(a2, a3);
    p.z = bfpack(a4, a5);
    p.w = bfpack(a6, a7);
    Yb4[(uint)node * 16u + o16] = p;
  }
}

// ---------------- MFMA GEMM: t2b[64 x 64] = x1b[64 x 128] @ W2, dinv epilogue -----

__global__ __launch_bounds__(256) void mgemm64_k(const unsigned short* __restrict__ Ab16,
                                                 const unsigned short* __restrict__ Wp,
                                                 unsigned short* __restrict__ Cb,
                                                 const float* __restrict__ dinv) {
  __shared__ uint4 Al4[64 * 16];  // 16 KB: 64 rows x 128 bf16 (swizzled)
  __shared__ uint4 Wl4[64 * 16];  // 16 KB packed W2 fragments
  char* Al = (char*)Al4;
  int tid = threadIdx.x;
  int row0 = blockIdx.x * 64;
  for (int i = tid; i < 64 * 16; i += 256) Wl4[i] = ((const uint4*)Wp)[i];
  const uint4* Ab = (const uint4*)Ab16;
  for (int i = tid; i < 64 * 16; i += 256) {
    int r = i >> 4, c8 = i & 15;
    int gr = row0 + r;
    uint4 v = make_uint4(0, 0, 0, 0);
    if (gr < N_NODES) v = Ab[(uint)gr * 16u + c8];
    int byte = (r * 256 + c8 * 16) ^ ((r & 7) << 4);
    *(uint4*)(Al + byte) = v;
  }
  __syncthreads();
  int lane = tid & 63, w = tid >> 6;
  f32x4 acc[4];
#pragma unroll
  for (int ct = 0; ct < 4; ct++) acc[ct] = (f32x4){0.f, 0.f, 0.f, 0.f};
  int arow = w * 16 + (lane & 15);
#pragma unroll
  for (int ks = 0; ks < 4; ks++) {
    int abyte = (arow * 256 + ks * 64 + (lane >> 4) * 16) ^ ((arow & 7) << 4);
    short8v a = *(const short8v*)(Al + abyte);
#pragma unroll
    for (int ct = 0; ct < 4; ct++) {
      short8v bb = *(const short8v*)((const char*)Wl4 + ((ks * 4 + ct) * 64 + lane) * 16);
      acc[ct] = __builtin_amdgcn_mfma_f32_16x16x32_bf16(a, bb, acc[ct], 0, 0, 0);
    }
  }
#pragma unroll
  for (int j = 0; j < 4; j++) {
    int grow = row0 + w * 16 + ((lane >> 4) << 2) + j;
    if (grow < N_NODES) {
      float scale = dinv[grow];
#pragma unroll
      for (int ct = 0; ct < 4; ct++) {
        Cb[(uint)grow * 64u + ct * 16 + (lane & 15)] =
            (unsigned short)bfrn(acc[ct][j] * scale);
      }
    }
  }
}

// ---------------- prop, 64 bf16 feats, 8 edges/wave-load (8 lanes x uint4) --------
// Row = 128 B = 8 lanes x 16 B. grp = lane>>3 (8 edges); o8 = lane&7 (8 feats).

__global__ __launch_bounds__(256) void prop64q8_k(const uint4* __restrict__ X4,  // bf16x8
                                                  float4* __restrict__ Y4,
                                                  const int* __restrict__ off,
                                                  const uint* __restrict__ cc,
                                                  const float* __restrict__ dinv) {
  int node = blockIdx.x * 4 + (threadIdx.x >> 6);
  if (node >= N_NODES) return;
  uint lane = threadIdx.x & 63u;
  uint grp = lane >> 3, o8 = lane & 7u;
  float di = dinv[node];
  uint4 s = X4[(uint)node * 8u + o8];
  float a0 = 0.f, a1 = 0.f, a2 = 0.f, a3 = 0.f, a4 = 0.f, a5 = 0.f, a6 = 0.f, a7 = 0.f;
  int e = off[node], e1 = off[node + 1];
  for (; e + 15 < e1; e += 16) {  // 2 x 8 edges, 2 row-loads in flight
    uint c0 = cc[e + grp], c1 = cc[e + 8 + grp];
    uint4 v0 = X4[c0 * 8u + o8];
    uint4 v1 = X4[c1 * 8u + o8];
    a0 += bflo(v0.x) + bflo(v1.x);
    a1 += bfhi(v0.x) + bfhi(v1.x);
    a2 += bflo(v0.y) + bflo(v1.y);
    a3 += bfhi(v0.y) + bfhi(v1.y);
    a4 += bflo(v0.z) + bflo(v1.z);
    a5 += bfhi(v0.z) + bfhi(v1.z);
    a6 += bflo(v0.w) + bflo(v1.w);
    a7 += bfhi(v0.w) + bfhi(v1.w);
  }
  for (; e + 7 < e1; e += 8) {  // 8 edges
    uint c0 = cc[e + grp];
    uint4 v0 = X4[c0 * 8u + o8];
    a0 += bflo(v0.x); a1 += bfhi(v0.x);
    a2 += bflo(v0.y); a3 += bfhi(v0.y);
    a4 += bflo(v0.z); a5 += bfhi(v0.z);
    a6 += bflo(v0.w); a7 += bfhi(v0.w);
  }
  if (e + (int)grp < e1) {  // tail 1..7 edges: group-masked
    uint c0 = cc[e + grp];
    uint4 v0 = X4[c0 * 8u + o8];
    a0 += bflo(v0.x); a1 += bfhi(v0.x);
    a2 += bflo(v0.y); a3 += bfhi(v0.y);
    a4 += bflo(v0.z); a5 += bfhi(v0.z);
    a6 += bflo(v0.w); a7 += bfhi(v0.w);
  }
  a0 += __shfl_xor(a0, 8);  a1 += __shfl_xor(a1, 8);
  a2 += __shfl_xor(a2, 8);  a3 += __shfl_xor(a3, 8);
  a4 += __shfl_xor(a4, 8);  a5 += __shfl_xor(a5, 8);
  a6 += __shfl_xor(a6, 8);  a7 += __shfl_xor(a7, 8);
  a0 += __shfl_xor(a0, 16); a1 += __shfl_xor(a1, 16);
  a2 += __shfl_xor(a2, 16); a3 += __shfl_xor(a3, 16);
  a4 += __shfl_xor(a4, 16); a5 += __shfl_xor(a5, 16);
  a6 += __shfl_xor(a6, 16); a7 += __shfl_xor(a7, 16);
  a0 += __shfl_xor(a0, 32); a1 += __shfl_xor(a1, 32);
  a2 += __shfl_xor(a2, 32); a3 += __shfl_xor(a3, 32);
  a4 += __shfl_xor(a4, 32); a5 += __shfl_xor(a5, 32);
  a6 += __shfl_xor(a6, 32); a7 += __shfl_xor(a7, 32);
  a0 = (a0 + bflo(s.x)) * di; a1 = (a1 + bfhi(s.x)) * di;
  a2 = (a2 + bflo(s.y)) * di; a3 = (a3 + bfhi(s.y)) * di;
  a4 = (a4 + bflo(s.z)) * di; a5 = (a5 + bfhi(s.z)) * di;
  a6 = (a6 + bflo(s.w)) * di; a7 = (a7 + bfhi(s.w)) * di;
  if (lane < 8) {
    float4 o0, o1;
    o0.x = a0; o0.y = a1; o0.z = a2; o0.w = a3;
    o1.x = a4; o1.y = a5; o1.z = a6; o1.w = a7;
    Y4[(uint)node * 16u + o8 * 2 + 0] = o0;
    Y4[(uint)node * 16u + o8 * 2 + 1] = o1;
  }
}

// ---------------- launch ----------------
// Pipeline (uses (PX)W == P(XW) and D^-1/2 factoring):
//   memset gcur; combo: binbuf bucket-sort + W01p/W2p packs
//   buckoff:  off/dinv/cc (CSR)
//   mgemm128: x0b = bf16(dinv ⊙ (feat@W01))    [MFMA]
//   prop128q: x1b = bf16(relu(dinv ⊙ gather(x0b)))
//   mgemm64:  t2b = bf16(dinv ⊙ (x1b @ W2))    [MFMA]
//   prop64q8: out = dinv ⊙ gather(t2b)          (fp32)

extern "C" void kernel_launch(void* const* d_in, const int* in_sizes, int n_in,
                              void* d_out, int out_size, void* d_ws, size_t ws_size,
                              hipStream_t stream) {
  const float* feat = (const float*)d_in[0];
  const int* ei = (const int*)d_in[1];  // int32 per harness contract
  const float* W0 = (const float*)d_in[2];
  const float* W1 = (const float*)d_in[3];
  const float* W2 = (const float*)d_in[4];
  float4* out = (float4*)d_out;

  char* ws = (char*)d_ws;
  unsigned short* x0b = (unsigned short*)ws; ws += (size_t)N_NODES * 128 * 2;  // 25.6 MB
  unsigned short* x1b = (unsigned short*)ws; ws += (size_t)N_NODES * 128 * 2;  // 25.6 MB
  unsigned short* t2b = (unsigned short*)ws; ws += (size_t)N_NODES * 64 * 2;   // 12.8 MB
  unsigned* binbuf = (unsigned*)ws;          ws += (size_t)NB * CAP * 4;       // 8.0 MB
  uint* cc = (uint*)ws;                      ws += (size_t)N_EDGES * 4;        // 6.4 MB
  float* dinv = (float*)ws;                  ws += (size_t)N_NODES * 4;
  int* off = (int*)ws;                       ws += (size_t)(N_NODES + 2) * 4;
  int* gcur = (int*)ws;                      ws += (size_t)NB * 4;
  unsigned short* W01p = (unsigned short*)ws; ws += 128 * 128 * 2;
  unsigned short* W2p = (unsigned short*)ws;  ws += 128 * 64 * 2;

  hipMemsetAsync(gcur, 0, (size_t)NB * 4, stream);
  combo_k<<<NBLK + 96, 256, 0, stream>>>(ei, gcur, binbuf, W0, W1, W2, W01p, W2p);
  buckoff_k<<<NB, 256, 0, stream>>>(binbuf, gcur, off, dinv, cc);
  mgemm128_k<<<(N_NODES + 63) / 64, 256, 0, stream>>>(feat, W01p, x0b, dinv);
  prop128q_k<true><<<(N_NODES + 3) / 4, 256, 0, stream>>>((const uint4*)x0b, (uint4*)x1b,
                                                          off, cc, dinv);
  mgemm64_k<<<(N_NODES + 63) / 64, 256, 0, stream>>>(x1b, W2p, t2b, dinv);
  prop64q8_k<<<(N_NODES + 3) / 4, 256, 0, stream>>>((const uint4*)t2b, out, off, cc, dinv);
}